// Round 6
// baseline (241.024 us; speedup 1.0000x reference)
//
#include <hip/hip_runtime.h>
#include <math.h>

#define HW 4096
#define CIN 256
#define BN_EPS 1e-5f
#define LOG2E 1.44269504088896f

typedef __attribute__((ext_vector_type(8))) short short8;
typedef __attribute__((ext_vector_type(4))) float floatx4;
typedef __attribute__((ext_vector_type(4))) unsigned short u16x4;
typedef unsigned short ushort;
typedef unsigned int u32;

__device__ inline ushort f2bf(float f) {
    union { float f; unsigned u; } c; c.f = f;
    unsigned r = c.u + 0x7fff + ((c.u >> 16) & 1);   // RNE; inputs are finite
    return (ushort)(r >> 16);
}
__device__ inline float bf2f(ushort u) {
    union { unsigned u; float f; } c; c.u = ((u32)u) << 16; return c.f;
}

// async global->LDS, 16B per lane. LDS dest must be wave-uniform base + lane*16.
__device__ inline void load_lds16(const ushort* g, ushort* l) {
    __builtin_amdgcn_global_load_lds(
        (const __attribute__((address_space(1))) u32*)g,
        (__attribute__((address_space(3))) u32*)l, 16, 0, 0);
}

// ---------------------------------------------------------------------------
// Fold BN into weights/bias, cast weights to bf16.  Q gets log2(e) folded in.
// Block 384 also zero-inits KmxU (atomicMax target).
// ---------------------------------------------------------------------------
__global__ __launch_bounds__(256) void prep_weights(
    const float* __restrict__ w1, const float* __restrict__ b1,
    const float* __restrict__ g1, const float* __restrict__ be1,
    const float* __restrict__ m1, const float* __restrict__ v1,
    const float* __restrict__ w2, const float* __restrict__ b2,
    const float* __restrict__ g2, const float* __restrict__ be2,
    const float* __restrict__ m2, const float* __restrict__ v2,
    const float* __restrict__ w3, const float* __restrict__ b3,
    const float* __restrict__ g3, const float* __restrict__ be3,
    const float* __restrict__ m3, const float* __restrict__ v3,
    ushort* __restrict__ w1c, ushort* __restrict__ w2c, ushort* __restrict__ w3c,
    float* __restrict__ bc, unsigned* __restrict__ KmxU)
{
    const int bid = blockIdx.x, tid = threadIdx.x;
    if (bid < 384) {
        int idx = bid * 256 + tid;
        if (idx < 16384) {
            int o = idx >> 8;
            float A = g1[o] * rsqrtf(v1[o] + BN_EPS) * LOG2E;
            w1c[idx] = f2bf(w1[idx] * A);
        } else if (idx < 32768) {
            int i2 = idx - 16384, o = i2 >> 8;
            float A = g2[o] * rsqrtf(v2[o] + BN_EPS);
            w2c[i2] = f2bf(w2[i2] * A);
        } else {
            int i3 = idx - 32768, o = i3 >> 8;
            float A = g3[o] * rsqrtf(v3[o] + BN_EPS);
            w3c[i3] = f2bf(w3[i3] * A);
        }
    } else {
        if (tid < 4) KmxU[tid] = 0u;
        if (tid < 64) {
            float A = g1[tid] * rsqrtf(v1[tid] + BN_EPS);
            bc[tid] = ((b1[tid] - m1[tid]) * A + be1[tid]) * LOG2E;
        } else if (tid < 128) {
            int o = tid - 64;
            float A = g2[o] * rsqrtf(v2[o] + BN_EPS);
            bc[tid] = (b2[o] - m2[o]) * A + be2[o];
        } else {
#pragma unroll
            for (int t = 0; t < 2; t++) {
                int o = (tid - 128) + t * 128;
                float A = g3[o] * rsqrtf(v3[o] + BN_EPS);
                bc[128 + o] = (b3[o] - m3[o]) * A + be3[o];
            }
        }
    }
}

// ---------------------------------------------------------------------------
// Q/K conv GEMM with fused fp32->bf16 transpose (reads x directly).
// Block: 128 px x 64 oc, K=256 in 4 chunks. 256 thr = 4 waves (wave = 32 px).
// Epilogue: Q -> row norms Qn; K -> per-batch max row norm (atomicMax).
// grid (32, 4, 2): z selects Q vs K.
// ---------------------------------------------------------------------------
__global__ __launch_bounds__(256) void gemm_qk(
    const float* __restrict__ x1, const float* __restrict__ x2,
    const ushort* __restrict__ w1c, const ushort* __restrict__ w2c,
    const float* __restrict__ bc, ushort* __restrict__ Qw, ushort* __restrict__ Kw,
    float* __restrict__ Qn, unsigned* __restrict__ KmxU)
{
    const int which = blockIdx.z;
    const float* x = which ? x2 : x1;
    const ushort* W = which ? w2c : w1c;
    const float* bias = bc + which * 64;
    ushort* out = which ? Kw : Qw;
    const int b = blockIdx.y;
    const int px0 = blockIdx.x << 7;

    __shared__ alignas(16) ushort Wl[64 * 64];
    __shared__ alignas(16) float Xf[64 * 132];
    __shared__ float redn[128];

    const int tid = threadIdx.x;
    const int lane = tid & 63;
    const int wv = tid >> 6;
    const int l15 = lane & 15, qd = lane >> 4;

    floatx4 acc[4][2];
#pragma unroll
    for (int mt = 0; mt < 4; mt++)
#pragma unroll
        for (int nt = 0; nt < 2; nt++) acc[mt][nt] = (floatx4){0.f, 0.f, 0.f, 0.f};

    for (int kk = 0; kk < 4; kk++) {
        const int k0 = kk << 6;
        __syncthreads();
#pragma unroll
        for (int t = 0; t < 2; t++) {                 // W tile (bf16, swizzled)
            int L = t * 256 + tid;
            int row = L >> 3, c8 = L & 7;
            load_lds16(W + row * 256 + k0 + ((c8 ^ (row & 7)) << 3), Wl + L * 8);
        }
#pragma unroll
        for (int t = 0; t < 8; t++) {                 // X tile fp32 [64c][128px+pad]
            int idx = t * 256 + tid;
            int row = idx >> 5, p4 = (idx & 31) << 2;
            *(float4*)&Xf[row * 132 + p4] =
                *(const float4*)&x[((size_t)(b * CIN + k0 + row) << 12) + px0 + p4];
        }
        __syncthreads();
#pragma unroll
        for (int kb = 0; kb < 2; kb++) {
            short8 af[4], bfr[2];
#pragma unroll
            for (int mt = 0; mt < 4; mt++) {
                int row = (mt << 4) + l15;
                af[mt] = *(const short8*)&Wl[(row << 6) + ((((kb << 2) + qd) ^ (row & 7)) << 3)];
            }
#pragma unroll
            for (int nt = 0; nt < 2; nt++) {
                int pxl = (wv << 5) + (nt << 4) + l15;
                alignas(16) ushort tmp[8];
#pragma unroll
                for (int j = 0; j < 8; j++)
                    tmp[j] = f2bf(Xf[((kb << 5) + (qd << 3) + j) * 132 + pxl]);
                bfr[nt] = *(short8*)tmp;
            }
#pragma unroll
            for (int mt = 0; mt < 4; mt++)
#pragma unroll
                for (int nt = 0; nt < 2; nt++)
                    acc[mt][nt] = __builtin_amdgcn_mfma_f32_16x16x32_bf16(
                        af[mt], bfr[nt], acc[mt][nt], 0, 0, 0);
        }
    }
    // epilogue: col(l15)=px, row(qd*4+r)=oc; plus row-norm stats
#pragma unroll
    for (int nt = 0; nt < 2; nt++) {
        int px = px0 + (wv << 5) + (nt << 4) + l15;
        float s2 = 0.f;
#pragma unroll
        for (int mt = 0; mt < 4; mt++) {
            alignas(8) ushort v4[4];
#pragma unroll
            for (int r = 0; r < 4; r++) {
                int oc = (mt << 4) + (qd << 2) + r;
                float y = fmaxf(acc[mt][nt][r] + bias[oc], 0.f);
                s2 += y * y;
                v4[r] = f2bf(y);
            }
            *(u16x4*)&out[(((size_t)(b * HW + px)) << 6) + (mt << 4) + (qd << 2)] = *(u16x4*)v4;
        }
        s2 += __shfl_xor(s2, 16);
        s2 += __shfl_xor(s2, 32);
        if (which == 0) {
            if (qd == 0) Qn[(b << 12) + px] = sqrtf(s2);
        } else {
            if (qd == 0) redn[(wv << 5) + (nt << 4) + l15] = s2;
        }
    }
    if (which == 1) {
        __syncthreads();
        if (tid < 128) {
            float v = redn[tid];
#pragma unroll
            for (int off = 1; off < 64; off <<= 1) v = fmaxf(v, __shfl_xor(v, off));
            if ((tid & 63) == 0) atomicMax(&KmxU[b], __float_as_uint(sqrtf(v)));
        }
    }
}

// ---------------------------------------------------------------------------
// V conv GEMM with fused transpose. 128 px x 128 oc per block, 4 waves (2x2).
// Output transposed: Vw[b][oc][px].  grid (32, 4, 2): z = oc-half.
// ---------------------------------------------------------------------------
__global__ __launch_bounds__(256) void gemm_v(
    const float* __restrict__ x3, const ushort* __restrict__ w3c,
    const float* __restrict__ bc, ushort* __restrict__ Vw)
{
    const int b = blockIdx.y;
    const int px0 = blockIdx.x << 7;
    const int oc0 = blockIdx.z << 7;
    const float* bias = bc + 128;

    __shared__ alignas(16) float Xf[64 * 132];
    __shared__ alignas(16) ushort Wl[128 * 64];

    const int tid = threadIdx.x;
    const int lane = tid & 63;
    const int wv = tid >> 6;
    const int l15 = lane & 15, qd = lane >> 4;
    const int wm0 = (wv & 1) << 6, wn0 = (wv >> 1) << 6;

    floatx4 acc[4][4];
#pragma unroll
    for (int mt = 0; mt < 4; mt++)
#pragma unroll
        for (int nt = 0; nt < 4; nt++) acc[mt][nt] = (floatx4){0.f, 0.f, 0.f, 0.f};

    for (int kk = 0; kk < 4; kk++) {
        const int k0 = kk << 6;
        __syncthreads();
#pragma unroll
        for (int t = 0; t < 4; t++) {                 // W tile 128 rows
            int L = t * 256 + tid;
            int row = L >> 3, c8 = L & 7;
            load_lds16(w3c + (oc0 + row) * 256 + k0 + ((c8 ^ (row & 7)) << 3), Wl + L * 8);
        }
#pragma unroll
        for (int t = 0; t < 8; t++) {                 // X tile fp32
            int idx = t * 256 + tid;
            int row = idx >> 5, p4 = (idx & 31) << 2;
            *(float4*)&Xf[row * 132 + p4] =
                *(const float4*)&x3[((size_t)(b * CIN + k0 + row) << 12) + px0 + p4];
        }
        __syncthreads();
#pragma unroll
        for (int kb = 0; kb < 2; kb++) {
            short8 af[4], bfr[4];
#pragma unroll
            for (int mt = 0; mt < 4; mt++) {
                int pxl = wm0 + (mt << 4) + l15;
                alignas(16) ushort tmp[8];
#pragma unroll
                for (int j = 0; j < 8; j++)
                    tmp[j] = f2bf(Xf[((kb << 5) + (qd << 3) + j) * 132 + pxl]);
                af[mt] = *(short8*)tmp;
            }
#pragma unroll
            for (int nt = 0; nt < 4; nt++) {
                int row = wn0 + (nt << 4) + l15;
                bfr[nt] = *(const short8*)&Wl[(row << 6) + ((((kb << 2) + qd) ^ (row & 7)) << 3)];
            }
#pragma unroll
            for (int mt = 0; mt < 4; mt++)
#pragma unroll
                for (int nt = 0; nt < 4; nt++)
                    acc[mt][nt] = __builtin_amdgcn_mfma_f32_16x16x32_bf16(
                        af[mt], bfr[nt], acc[mt][nt], 0, 0, 0);
        }
    }
    // epilogue: col(l15)=oc, row(qd*4+r)=px
#pragma unroll
    for (int nt = 0; nt < 4; nt++) {
        int oc = oc0 + wn0 + (nt << 4) + l15;
        float bv = bias[oc];
#pragma unroll
        for (int mt = 0; mt < 4; mt++) {
            alignas(8) ushort v4[4];
#pragma unroll
            for (int r = 0; r < 4; r++)
                v4[r] = f2bf(fmaxf(acc[mt][nt][r] + bv, 0.f));
            size_t base = (((size_t)(b * CIN + oc)) << 12) + px0 + wm0 + (mt << 4) + (qd << 2);
            *(u16x4*)&Vw[base] = *(u16x4*)v4;
        }
    }
}

// ---------------------------------------------------------------------------
// Flash v3: i-tile 128, j-split x2, fixed softmax bound M_i = |Q_i|*max|K_j|
// (valid: ReLU => S>=0; Mi ~ 50 << 126 so exp2(S-Mi) in [2^-126, ~1] always).
// No online max, no rescale, no in-loop cross-lane reductions.
// 8 waves: wave wv owns S^T rows for i-seg 16*wv (dedup, zero redundancy);
// PV role (iw=wv&1 -> 64 i, ch=wv>>1 -> 64 c): 4x4 acc tiles.
// K/V double-buffered (2x40KB); prefetch issued after the P-barrier.
// R6 fix: partial-store channel offset is ch*64 (matches PV A-frag rows),
// NOT ch*128 — ch<<7 wrote past the row and corrupted Op/mlM/mlL.
// ---------------------------------------------------------------------------
__global__ __launch_bounds__(512, 2) void flash_mfma(
    const ushort* __restrict__ Q, const ushort* __restrict__ K,
    const ushort* __restrict__ Vtg, const float* __restrict__ Qn,
    const unsigned* __restrict__ KmxU, ushort* __restrict__ Op0,
    ushort* __restrict__ Op1, float* __restrict__ mlM, float* __restrict__ mlL)
{
    const int tid = threadIdx.x;
    const int lane = tid & 63;
    const int wv = tid >> 6;
    const int iw = wv & 1, ch = wv >> 1;
    const int l15 = lane & 15, qd = lane >> 4;
    const int sw = l15 & 7;

    const int bid = blockIdx.x;
    const int s = bid & 1;                   // j-split (XCD-affine with b)
    const int b = (bid >> 1) & 3;
    const int it = bid >> 3;                 // 0..31
    const int i0 = it << 7;
    const int jbeg = s << 11;

    __shared__ alignas(16) ushort KV[2][20480];   // per buf: Kt 64x64 | Vt 256x64
    __shared__ alignas(16) ushort Pt[128 * 64];   // [i][j] bf16, swizzled

    const float kmx = __uint_as_float(KmxU[b]);
    const int iS = i0 + (wv << 4) + l15;          // S-owner row
    const float Mi = Qn[(b << 12) + iS] * kmx;

    short8 qf[2];
#pragma unroll
    for (int kb = 0; kb < 2; kb++)
        qf[kb] = *(const short8*)(Q + (((size_t)((b << 12) + iS)) << 6) + kb * 32 + qd * 8);

    const floatx4 zv = {0.f, 0.f, 0.f, 0.f};
    floatx4 acc[4][4];
#pragma unroll
    for (int ct = 0; ct < 4; ct++)
#pragma unroll
        for (int is = 0; is < 4; is++) acc[ct][is] = zv;
    float lsum = 0.f;

#define STAGE(BUF, J0)                                                           \
    {                                                                            \
        int row = tid >> 3, c8 = tid & 7;                                        \
        load_lds16(K + (((size_t)((b << 12) + (J0) + row)) << 6) +               \
                       ((c8 ^ (row & 7)) << 3), KV[BUF] + tid * 8);              \
        _Pragma("unroll")                                                        \
        for (int t2 = 0; t2 < 4; t2++) {                                         \
            int idx = tid + (t2 << 9);                                           \
            int vr = idx >> 3, vc = idx & 7;                                     \
            load_lds16(Vtg + (((size_t)((b << 8) + vr)) << 12) + (J0) +          \
                           ((vc ^ (vr & 7)) << 3), KV[BUF] + 4096 + idx * 8);    \
        }                                                                        \
    }

    STAGE(0, jbeg)

    for (int jj = 0; jj < 32; jj++) {
        __syncthreads();                          // B1: buf(jj) staged, prev PV done
        const ushort* Kt = KV[jj & 1];
        const ushort* Vt = KV[jj & 1] + 4096;

        // ---- S^T[64j][16i of wv]: 8 MFMA, no redundancy
        floatx4 st[4];
#pragma unroll
        for (int jt = 0; jt < 4; jt++) st[jt] = zv;
#pragma unroll
        for (int kb = 0; kb < 2; kb++) {
            const int csel = (((kb << 2) + qd) ^ sw) << 3;
#pragma unroll
            for (int jt = 0; jt < 4; jt++) {
                short8 kf = *(const short8*)&Kt[(((jt << 4) + l15) << 6) + csel];
                st[jt] = __builtin_amdgcn_mfma_f32_16x16x32_bf16(kf, qf[kb], st[jt], 0, 0, 0);
            }
        }

        // ---- p = exp2(S - Mi); accumulate l; write P rows (swizzled b64)
        const int prow = (wv << 4) + l15;
#pragma unroll
        for (int jt = 0; jt < 4; jt++) {
            float p0 = exp2f(st[jt][0] - Mi);
            float p1 = exp2f(st[jt][1] - Mi);
            float p2 = exp2f(st[jt][2] - Mi);
            float p3 = exp2f(st[jt][3] - Mi);
            lsum += (p0 + p1) + (p2 + p3);
            alignas(8) ushort pk[4] = {f2bf(p0), f2bf(p1), f2bf(p2), f2bf(p3)};
            int c8 = (jt << 1) + (qd >> 1);
            *(u16x4*)&Pt[(prow << 6) + ((c8 ^ (prow & 7)) << 3) + ((qd & 1) << 2)] =
                *(u16x4*)pk;
        }
        __syncthreads();                          // B2: P visible

        if (jj + 1 < 32) STAGE((jj + 1) & 1, jbeg + ((jj + 1) << 6))

        // ---- PV: O^T[64c of ch][64i of iw] += V^T P^T
#pragma unroll
        for (int kb = 0; kb < 2; kb++) {
            const int csel = (((kb << 2) + qd) ^ sw) << 3;
            short8 pf[4];
#pragma unroll
            for (int is = 0; is < 4; is++)
                pf[is] = *(const short8*)&Pt[(((iw << 6) + (is << 4) + l15) << 6) + csel];
#pragma unroll
            for (int ct = 0; ct < 4; ct++) {
                short8 vf = *(const short8*)&Vt[(((ch << 6) + (ct << 4) + l15) << 6) + csel];
#pragma unroll
                for (int is = 0; is < 4; is++)
                    acc[ct][is] = __builtin_amdgcn_mfma_f32_16x16x32_bf16(
                        vf, pf[is], acc[ct][is], 0, 0, 0);
            }
        }
    }
#undef STAGE

    // ---- final l reduction (once), partial store
    lsum += __shfl_xor(lsum, 16);
    lsum += __shfl_xor(lsum, 32);

    ushort* Op = s ? Op1 : Op0;
#pragma unroll
    for (int is = 0; is < 4; is++) {
        int i = i0 + (iw << 6) + (is << 4) + l15;
        size_t obase = (((size_t)((b << 12) + i)) << 8);
#pragma unroll
        for (int ct = 0; ct < 4; ct++) {
            alignas(8) ushort pk[4];
#pragma unroll
            for (int r = 0; r < 4; r++) pk[r] = f2bf(acc[ct][is][r]);
            *(u16x4*)&Op[obase + (ch << 6) + (ct << 4) + (qd << 2)] = *(u16x4*)pk;
        }
    }
    if (qd == 0) {
        int mi2 = (s << 14) + (b << 12) + iS;
        mlM[mi2] = Mi;
        mlL[mi2] = lsum;
    }
}

// ---------------------------------------------------------------------------
// Merge 2 j-split partials + gam/l normalize + residual; [b][i][c]->[b][c][i].
// ---------------------------------------------------------------------------
__global__ __launch_bounds__(256) void merge_out(
    const ushort* __restrict__ Op0, const ushort* __restrict__ Op1,
    const float* __restrict__ mlM, const float* __restrict__ mlL,
    const float* __restrict__ x1, const float* __restrict__ gam,
    float* __restrict__ out)
{
    const int b = blockIdx.z, c0 = blockIdx.y << 6, i0 = blockIdx.x << 6;
    const int tid = threadIdx.x;

    __shared__ float Tl[64][65];
    __shared__ float a0s[64], a1s[64];

    if (tid < 64) {
        int gi = (b << 12) + i0 + tid;
        float m0 = mlM[gi], m1 = mlM[16384 + gi];
        float l0 = mlL[gi], l1 = mlL[16384 + gi];
        float M = fmaxf(m0, m1);
        float w0 = exp2f(m0 - M), w1 = exp2f(m1 - M);
        float gd = gam[0] / (w0 * l0 + w1 * l1);
        a0s[tid] = w0 * gd;
        a1s[tid] = w1 * gd;
    }
    __syncthreads();
#pragma unroll
    for (int k = 0; k < 4; k++) {
        int idx4 = tid + (k << 8);
        int i = idx4 >> 4, c4 = (idx4 & 15) << 2;
        size_t g = ((size_t)((b << 12) + i0 + i)) * 256 + c0 + c4;
        u16x4 p0 = *(const u16x4*)&Op0[g];
        u16x4 p1 = *(const u16x4*)&Op1[g];
        float A0 = a0s[i], A1 = a1s[i];
#pragma unroll
        for (int r = 0; r < 4; r++)
            Tl[c4 + r][i] = A0 * bf2f(p0[r]) + A1 * bf2f(p1[r]);
    }
    __syncthreads();
#pragma unroll
    for (int k = 0; k < 4; k++) {
        int idx4 = tid + (k << 8);
        int c = idx4 >> 4, i4 = (idx4 & 15) << 2;
        size_t g = (((size_t)(b * CIN + c0 + c)) << 12) + i0 + i4;
        float4 xv = *(const float4*)&x1[g];
        float4 o;
        o.x = Tl[c][i4 + 0] + xv.x;
        o.y = Tl[c][i4 + 1] + xv.y;
        o.z = Tl[c][i4 + 2] + xv.z;
        o.w = Tl[c][i4 + 3] + xv.w;
        *(float4*)&out[g] = o;
    }
}

// ---------------------------------------------------------------------------
extern "C" void kernel_launch(void* const* d_in, const int* in_sizes, int n_in,
                              void* d_out, int out_size, void* d_ws, size_t ws_size,
                              hipStream_t stream)
{
    const float* x1  = (const float*)d_in[0];
    const float* x2  = (const float*)d_in[1];
    const float* x3  = (const float*)d_in[2];
    const float* w1  = (const float*)d_in[3];
    const float* b1  = (const float*)d_in[4];
    const float* g1  = (const float*)d_in[5];
    const float* be1 = (const float*)d_in[6];
    const float* m1  = (const float*)d_in[7];
    const float* v1  = (const float*)d_in[8];
    const float* w2  = (const float*)d_in[9];
    const float* b2  = (const float*)d_in[10];
    const float* g2  = (const float*)d_in[11];
    const float* be2 = (const float*)d_in[12];
    const float* m2  = (const float*)d_in[13];
    const float* v2  = (const float*)d_in[14];
    const float* w3  = (const float*)d_in[15];
    const float* b3  = (const float*)d_in[16];
    const float* g3  = (const float*)d_in[17];
    const float* be3 = (const float*)d_in[18];
    const float* m3  = (const float*)d_in[19];
    const float* v3  = (const float*)d_in[20];
    const float* gam = (const float*)d_in[21];

    ushort* Qw  = (ushort*)d_ws;                     // 1M elems, 2 MB
    ushort* Kw  = Qw  + (size_t)1048576;             // 2 MB
    ushort* Vw  = Kw  + (size_t)1048576;             // 4M elems, 8 MB
    ushort* w1c = Vw  + (size_t)4194304;
    ushort* w2c = w1c + 16384;
    ushort* w3c = w2c + 16384;
    float*  bc  = (float*)(w3c + 65536);             // 384 floats
    float*  Qn  = bc + 384;                          // 16384 floats
    unsigned* KmxU = (unsigned*)(Qn + 16384);        // 4
    ushort* Op0 = (ushort*)(KmxU + 4);               // 4M elems, 8 MB
    ushort* Op1 = Op0 + (size_t)4194304;             // 8 MB
    float*  mlM = (float*)(Op1 + (size_t)4194304);   // 32768 floats
    float*  mlL = mlM + 32768;

    prep_weights<<<385, 256, 0, stream>>>(w1, b1, g1, be1, m1, v1,
                                          w2, b2, g2, be2, m2, v2,
                                          w3, b3, g3, be3, m3, v3,
                                          w1c, w2c, w3c, bc, KmxU);
    gemm_qk<<<dim3(32, 4, 2), 256, 0, stream>>>(x1, x2, w1c, w2c, bc, Qw, Kw, Qn, KmxU);
    gemm_v <<<dim3(32, 4, 2), 256, 0, stream>>>(x3, w3c, bc, Vw);
    flash_mfma<<<256, 512, 0, stream>>>(Qw, Kw, Vw, Qn, KmxU, Op0, Op1, mlM, mlL);
    merge_out<<<dim3(64, 4, 4), 256, 0, stream>>>(Op0, Op1, mlM, mlL, x1, gam, (float*)d_out);
}

// Round 7
// 213.737 us; speedup vs baseline: 1.1277x; 1.1277x over previous
//
#include <hip/hip_runtime.h>
#include <math.h>

#define HW 4096
#define CIN 256
#define BN_EPS 1e-5f
#define LOG2E 1.44269504088896f

typedef __attribute__((ext_vector_type(8))) short short8;
typedef __attribute__((ext_vector_type(4))) float floatx4;
typedef __attribute__((ext_vector_type(4))) unsigned short u16x4;
typedef unsigned short ushort;
typedef unsigned int u32;

__device__ inline ushort f2bf(float f) {
    union { float f; unsigned u; } c; c.f = f;
    unsigned r = c.u + 0x7fff + ((c.u >> 16) & 1);   // RNE; inputs are finite
    return (ushort)(r >> 16);
}
__device__ inline float bf2f(ushort u) {
    union { unsigned u; float f; } c; c.u = ((u32)u) << 16; return c.f;
}

// async global->LDS, 16B per lane. LDS dest must be wave-uniform base + lane*16.
__device__ inline void load_lds16(const ushort* g, ushort* l) {
    __builtin_amdgcn_global_load_lds(
        (const __attribute__((address_space(1))) u32*)g,
        (__attribute__((address_space(3))) u32*)l, 16, 0, 0);
}

// ---------------------------------------------------------------------------
// z<12: x (fp32, [b][c][hw]) -> Xt (bf16, [b][hw][c]) 64x64 LDS transpose.
// z==12: fold BN into weights/bias (bf16 W, fp32 bias), zero KmxU.
// grid (64, 4, 13), 256 thr.
// ---------------------------------------------------------------------------
__global__ __launch_bounds__(256) void fuse_tp(
    const float* __restrict__ x1, const float* __restrict__ x2,
    const float* __restrict__ x3,
    const float* __restrict__ w1, const float* __restrict__ b1,
    const float* __restrict__ g1, const float* __restrict__ be1,
    const float* __restrict__ m1, const float* __restrict__ v1,
    const float* __restrict__ w2, const float* __restrict__ b2,
    const float* __restrict__ g2, const float* __restrict__ be2,
    const float* __restrict__ m2, const float* __restrict__ v2,
    const float* __restrict__ w3, const float* __restrict__ b3,
    const float* __restrict__ g3, const float* __restrict__ be3,
    const float* __restrict__ m3, const float* __restrict__ v3,
    ushort* __restrict__ Xt1, ushort* __restrict__ Xt2, ushort* __restrict__ Xt3,
    ushort* __restrict__ w1c, ushort* __restrict__ w2c, ushort* __restrict__ w3c,
    float* __restrict__ bc, unsigned* __restrict__ KmxU)
{
    const int z = blockIdx.z;
    const int tid = threadIdx.x;

    __shared__ float t[64 * 65];

    if (z == 12) {
        int pid = blockIdx.y * 64 + blockIdx.x;      // 0..255
        int g0 = pid * 256 + tid;                     // 0..65535
        for (int g = g0; g < 98304; g += 65536) {
            if (g < 16384) {
                int o = g >> 8;
                float A = g1[o] * rsqrtf(v1[o] + BN_EPS) * LOG2E;
                w1c[g] = f2bf(w1[g] * A);
            } else if (g < 32768) {
                int i2 = g - 16384, o = i2 >> 8;
                float A = g2[o] * rsqrtf(v2[o] + BN_EPS);
                w2c[i2] = f2bf(w2[i2] * A);
            } else {
                int i3 = g - 32768, o = i3 >> 8;
                float A = g3[o] * rsqrtf(v3[o] + BN_EPS);
                w3c[i3] = f2bf(w3[i3] * A);
            }
        }
        if (g0 < 4) KmxU[g0] = 0u;
        if (g0 < 64) {
            float A = g1[g0] * rsqrtf(v1[g0] + BN_EPS);
            bc[g0] = ((b1[g0] - m1[g0]) * A + be1[g0]) * LOG2E;
        } else if (g0 < 128) {
            int o = g0 - 64;
            float A = g2[o] * rsqrtf(v2[o] + BN_EPS);
            bc[g0] = (b2[o] - m2[o]) * A + be2[o];
        } else if (g0 < 384) {
            int o = g0 - 128;
            float A = g3[o] * rsqrtf(v3[o] + BN_EPS);
            bc[128 + o] = (b3[o] - m3[o]) * A + be3[o];
        }
        return;
    }

    const int inp = z >> 2, b = z & 3;
    const float* x = inp == 0 ? x1 : (inp == 1 ? x2 : x3);
    ushort* o = inp == 0 ? Xt1 : (inp == 1 ? Xt2 : Xt3);
    const int c0 = blockIdx.y << 6, p0 = blockIdx.x << 6;

    const int col = tid & 63, r4 = tid >> 6;
#pragma unroll
    for (int t2 = 0; t2 < 16; t2++) {
        int row = (t2 << 2) + r4;
        t[row * 65 + col] = x[((size_t)(b * CIN + c0 + row) << 12) + p0 + col];
    }
    __syncthreads();
    const int p = tid >> 2, cs = (tid & 3) << 4;
    alignas(16) ushort v[16];
#pragma unroll
    for (int k = 0; k < 16; k++) v[k] = f2bf(t[(cs + k) * 65 + p]);
    size_t base = ((size_t)(b * HW + p0 + p)) * 256 + c0 + cs;
    *(short8*)&o[base]     = *(short8*)&v[0];
    *(short8*)&o[base + 8] = *(short8*)&v[8];
}

// ---------------------------------------------------------------------------
// Unified conv GEMMs, bf16 in/out, px-tile 64, K=256 in 4 chunks.
// grid (64, 4, 4): z=0 Q (Xt1,w1c -> Qw[b][px][64] + Qn row norms),
//                  z=1 K (Xt2,w2c -> Kw + per-batch max norm atomicMax),
//                  z=2,3 V oc-halves (Xt3,w3c -> Vw[b][oc][px] transposed).
// ---------------------------------------------------------------------------
__global__ __launch_bounds__(256) void gemm_qkv(
    const ushort* __restrict__ Xt1, const ushort* __restrict__ Xt2,
    const ushort* __restrict__ Xt3,
    const ushort* __restrict__ w1c, const ushort* __restrict__ w2c,
    const ushort* __restrict__ w3c, const float* __restrict__ bc,
    ushort* __restrict__ Qw, ushort* __restrict__ Kw, ushort* __restrict__ Vw,
    float* __restrict__ Qn, unsigned* __restrict__ KmxU)
{
    const int z = blockIdx.z;
    const int b = blockIdx.y;
    const int px0 = blockIdx.x << 6;
    const int tid = threadIdx.x, lane = tid & 63, wv = tid >> 6;
    const int l15 = lane & 15, qd = lane >> 4;
    const int sw = l15 & 7;

    __shared__ alignas(16) ushort Xl[64 * 64];
    __shared__ alignas(16) ushort Wl[128 * 64];

    if (z < 2) {
        const ushort* X = z ? Xt2 : Xt1;
        const ushort* W = z ? w2c : w1c;
        const float* bias = bc + (z << 6);
        ushort* out = z ? Kw : Qw;
        const int n0w = wv << 4;

        floatx4 acc[4];
#pragma unroll
        for (int mt = 0; mt < 4; mt++) acc[mt] = (floatx4){0.f, 0.f, 0.f, 0.f};

        for (int kk = 0; kk < 4; kk++) {
            const int k0 = kk << 6;
            __syncthreads();
#pragma unroll
            for (int t = 0; t < 2; t++) {
                int L = t * 256 + tid;
                int row = L >> 3, c8 = L & 7;
                load_lds16(W + row * 256 + k0 + ((c8 ^ (row & 7)) << 3), Wl + L * 8);
                load_lds16(X + ((size_t)((b << 12) + px0 + row)) * 256 + k0 +
                               ((c8 ^ (row & 7)) << 3), Xl + L * 8);
            }
            __syncthreads();
#pragma unroll
            for (int kb = 0; kb < 2; kb++) {
                const int csel = (((kb << 2) + qd) ^ sw) << 3;
                short8 bfr = *(const short8*)&Xl[((n0w + l15) << 6) + csel];
#pragma unroll
                for (int mt = 0; mt < 4; mt++) {
                    short8 af = *(const short8*)&Wl[(((mt << 4) + l15) << 6) + csel];
                    acc[mt] = __builtin_amdgcn_mfma_f32_16x16x32_bf16(af, bfr, acc[mt], 0, 0, 0);
                }
            }
        }
        const int px = px0 + n0w + l15;
        float s2 = 0.f;
#pragma unroll
        for (int mt = 0; mt < 4; mt++) {
            alignas(8) ushort v4[4];
#pragma unroll
            for (int r = 0; r < 4; r++) {
                int oc = (mt << 4) + (qd << 2) + r;
                float y = fmaxf(acc[mt][r] + bias[oc], 0.f);
                s2 += y * y;
                v4[r] = f2bf(y);
            }
            *(u16x4*)&out[(((size_t)((b << 12) + px)) << 6) + (mt << 4) + (qd << 2)] =
                *(u16x4*)v4;
        }
        s2 += __shfl_xor(s2, 16);
        s2 += __shfl_xor(s2, 32);
        if (z == 0) {
            if (qd == 0) Qn[(b << 12) + px] = sqrtf(s2);
        } else {
#pragma unroll
            for (int off = 1; off < 16; off <<= 1) s2 = fmaxf(s2, __shfl_xor(s2, off));
            if (lane == 0) atomicMax(KmxU + b, __float_as_uint(sqrtf(s2)));
        }
    } else {
        const int oc0 = (z - 2) << 7;
        const float* bias = bc + 128;
        const int wm0 = (wv & 1) << 5, wn0 = (wv >> 1) << 6;

        floatx4 acc[2][4];
#pragma unroll
        for (int mt = 0; mt < 2; mt++)
#pragma unroll
            for (int nt = 0; nt < 4; nt++) acc[mt][nt] = (floatx4){0.f, 0.f, 0.f, 0.f};

        for (int kk = 0; kk < 4; kk++) {
            const int k0 = kk << 6;
            __syncthreads();
#pragma unroll
            for (int t = 0; t < 2; t++) {
                int L = t * 256 + tid;
                int row = L >> 3, c8 = L & 7;
                load_lds16(Xt3 + ((size_t)((b << 12) + px0 + row)) * 256 + k0 +
                               ((c8 ^ (row & 7)) << 3), Xl + L * 8);
            }
#pragma unroll
            for (int t = 0; t < 4; t++) {
                int L = t * 256 + tid;
                int row = L >> 3, c8 = L & 7;
                load_lds16(w3c + (oc0 + row) * 256 + k0 + ((c8 ^ (row & 7)) << 3), Wl + L * 8);
            }
            __syncthreads();
#pragma unroll
            for (int kb = 0; kb < 2; kb++) {
                const int csel = (((kb << 2) + qd) ^ sw) << 3;
                short8 af[2], bfr[4];
#pragma unroll
                for (int mt = 0; mt < 2; mt++)
                    af[mt] = *(const short8*)&Xl[((wm0 + (mt << 4) + l15) << 6) + csel];
#pragma unroll
                for (int nt = 0; nt < 4; nt++)
                    bfr[nt] = *(const short8*)&Wl[((wn0 + (nt << 4) + l15) << 6) + csel];
#pragma unroll
                for (int mt = 0; mt < 2; mt++)
#pragma unroll
                    for (int nt = 0; nt < 4; nt++)
                        acc[mt][nt] = __builtin_amdgcn_mfma_f32_16x16x32_bf16(
                            af[mt], bfr[nt], acc[mt][nt], 0, 0, 0);
            }
        }
#pragma unroll
        for (int nt = 0; nt < 4; nt++) {
            int oc = oc0 + wn0 + (nt << 4) + l15;
            float bv = bias[oc];
#pragma unroll
            for (int mt = 0; mt < 2; mt++) {
                alignas(8) ushort v4[4];
#pragma unroll
                for (int r = 0; r < 4; r++)
                    v4[r] = f2bf(fmaxf(acc[mt][nt][r] + bv, 0.f));
                size_t base = (((size_t)(b * CIN + oc)) << 12) + px0 + wm0 + (mt << 4) + (qd << 2);
                *(u16x4*)&Vw[base] = *(u16x4*)v4;
            }
        }
    }
}

// ---------------------------------------------------------------------------
// Flash v4: 1024 thr = 16 waves (4 waves/SIMD), i-tile 128, j-split x2.
// Single-buffered K/V (56 KB total LDS) with rotated staging: K(i+1) issued
// after the P-barrier (Kt free once S done), V(i+1) after the PV-barrier —
// 2 barriers/iter, each staging op gets a full compute phase before drain.
// S dedup: wave (jh = wv>>3, si = (wv&7)*16) owns S^T[32j][16i] (no dup).
// PV: wave (ch = wv>>1 -> 32c, iw = wv&1 -> 64i), acc 2x4.
// Fixed softmax bound Mi = |Q_i|*max|K_j| (ReLU => S>=0; no online max).
// ---------------------------------------------------------------------------
__global__ __launch_bounds__(1024, 4) void flash_mfma(
    const ushort* __restrict__ Q, const ushort* __restrict__ K,
    const ushort* __restrict__ Vtg, const float* __restrict__ Qn,
    const unsigned* __restrict__ KmxU, ushort* __restrict__ Op0,
    ushort* __restrict__ Op1, float* __restrict__ mlM, float* __restrict__ mlL)
{
    const int tid = threadIdx.x;
    const int lane = tid & 63;
    const int wv = tid >> 6;                 // 0..15
    const int l15 = lane & 15, qd = lane >> 4;
    const int sw = l15 & 7;
    const int jh = wv >> 3;                  // S: j-half (32 j)
    const int si = (wv & 7) << 4;            // S: i-seg base
    const int iw = wv & 1, ch = wv >> 1;     // PV: 64-i block, 32-c block

    const int bid = blockIdx.x;
    const int s = bid & 1;
    const int b = (bid >> 1) & 3;
    const int i0 = (bid >> 3) << 7;
    const int jbeg = s << 11;

    __shared__ alignas(16) ushort Kt[64 * 64];     //  8 KB
    __shared__ alignas(16) ushort Vt[256 * 64];    // 32 KB
    __shared__ alignas(16) ushort Pt[128 * 64];    // 16 KB
    __shared__ float lred[2][128];

    const float kmx = __uint_as_float(KmxU[b]);
    const int iS = i0 + si + l15;
    const float Mi = Qn[(b << 12) + iS] * kmx;

    short8 qf[2];
#pragma unroll
    for (int kb = 0; kb < 2; kb++)
        qf[kb] = *(const short8*)(Q + (((size_t)((b << 12) + iS)) << 6) + kb * 32 + qd * 8);

    const floatx4 zv = {0.f, 0.f, 0.f, 0.f};
    floatx4 acc[2][4];
#pragma unroll
    for (int ct = 0; ct < 2; ct++)
#pragma unroll
        for (int is = 0; is < 4; is++) acc[ct][is] = zv;
    float lsum = 0.f;

#define STAGE_K(J0)                                                              \
    if (tid < 512) {                                                             \
        int row = tid >> 3, c8 = tid & 7;                                        \
        load_lds16(K + (((size_t)((b << 12) + (J0) + row)) << 6) +               \
                       ((c8 ^ (row & 7)) << 3), Kt + tid * 8);                   \
    }
#define STAGE_V(J0)                                                              \
    {                                                                            \
        _Pragma("unroll")                                                        \
        for (int t2 = 0; t2 < 2; t2++) {                                         \
            int idx = tid + (t2 << 10);                                          \
            int vr = idx >> 3, vc = idx & 7;                                     \
            load_lds16(Vtg + (((size_t)((b << 8) + vr)) << 12) + (J0) +          \
                           ((vc ^ (vr & 7)) << 3), Vt + idx * 8);                \
        }                                                                        \
    }

    STAGE_K(jbeg)
    STAGE_V(jbeg)
    __syncthreads();

    for (int jj = 0; jj < 32; jj++) {
        const int j0n = jbeg + ((jj + 1) << 6);

        // ---- S^T[32j of jh][16i of si]: 4 MFMA, 4 kf reads, Q in regs
        floatx4 st[2] = {zv, zv};
#pragma unroll
        for (int kb = 0; kb < 2; kb++) {
            const int csel = (((kb << 2) + qd) ^ sw) << 3;
#pragma unroll
            for (int jt = 0; jt < 2; jt++) {
                short8 kf = *(const short8*)&Kt[(((jh << 5) + (jt << 4) + l15) << 6) + csel];
                st[jt] = __builtin_amdgcn_mfma_f32_16x16x32_bf16(kf, qf[kb], st[jt], 0, 0, 0);
            }
        }

        // ---- p = exp2(S - Mi); lsum; P rows (swizzled b64)
        const int prow = si + l15;
#pragma unroll
        for (int jt = 0; jt < 2; jt++) {
            float p0 = exp2f(st[jt][0] - Mi);
            float p1 = exp2f(st[jt][1] - Mi);
            float p2 = exp2f(st[jt][2] - Mi);
            float p3 = exp2f(st[jt][3] - Mi);
            lsum += (p0 + p1) + (p2 + p3);
            alignas(8) ushort pk[4] = {f2bf(p0), f2bf(p1), f2bf(p2), f2bf(p3)};
            int c8 = (jh << 2) + (jt << 1) + (qd >> 1);
            *(u16x4*)&Pt[(prow << 6) + ((c8 ^ sw) << 3) + ((qd & 1) << 2)] = *(u16x4*)pk;
        }
        __syncthreads();                     // B2: P visible; Kt free; V(jj) drained

        if (jj + 1 < 32) STAGE_K(j0n)

        // ---- PV: O^T[32c of ch][64i of iw] += V^T P^T  (16 MFMA, 12 reads)
#pragma unroll
        for (int kb = 0; kb < 2; kb++) {
            const int csel = (((kb << 2) + qd) ^ sw) << 3;
            short8 vf[2], pf[4];
#pragma unroll
            for (int ct = 0; ct < 2; ct++)
                vf[ct] = *(const short8*)&Vt[(((ch << 5) + (ct << 4) + l15) << 6) + csel];
#pragma unroll
            for (int is = 0; is < 4; is++)
                pf[is] = *(const short8*)&Pt[(((iw << 6) + (is << 4) + l15) << 6) + csel];
#pragma unroll
            for (int ct = 0; ct < 2; ct++)
#pragma unroll
                for (int is = 0; is < 4; is++)
                    acc[ct][is] = __builtin_amdgcn_mfma_f32_16x16x32_bf16(
                        vf[ct], pf[is], acc[ct][is], 0, 0, 0);
        }
        __syncthreads();                     // B3: Vt,Pt free; drains K(jj+1)

        if (jj + 1 < 32) STAGE_V(j0n)
    }
#undef STAGE_K
#undef STAGE_V

    // ---- l reduction (once): qd-combine, then jh-combine via LDS
    lsum += __shfl_xor(lsum, 16);
    lsum += __shfl_xor(lsum, 32);
    if (qd == 0) lred[jh][si + l15] = lsum;
    __syncthreads();

    ushort* Op = s ? Op1 : Op0;
#pragma unroll
    for (int is = 0; is < 4; is++) {
        int i = i0 + (iw << 6) + (is << 4) + l15;
        size_t obase = (((size_t)((b << 12) + i)) << 8);
#pragma unroll
        for (int ct = 0; ct < 2; ct++) {
            alignas(8) ushort pk[4];
#pragma unroll
            for (int r = 0; r < 4; r++) pk[r] = f2bf(acc[ct][is][r]);
            *(u16x4*)&Op[obase + (ch << 5) + (ct << 4) + (qd << 2)] = *(u16x4*)pk;
        }
    }
    if (jh == 0 && qd == 0) {
        int mi2 = (s << 14) + (b << 12) + iS;
        mlM[mi2] = Mi;
        mlL[mi2] = lred[0][si + l15] + lred[1][si + l15];
    }
}

// ---------------------------------------------------------------------------
// Merge 2 j-split partials + gam/l normalize + residual; [b][i][c]->[b][c][i].
// ---------------------------------------------------------------------------
__global__ __launch_bounds__(256) void merge_out(
    const ushort* __restrict__ Op0, const ushort* __restrict__ Op1,
    const float* __restrict__ mlM, const float* __restrict__ mlL,
    const float* __restrict__ x1, const float* __restrict__ gam,
    float* __restrict__ out)
{
    const int b = blockIdx.z, c0 = blockIdx.y << 6, i0 = blockIdx.x << 6;
    const int tid = threadIdx.x;

    __shared__ float Tl[64][65];
    __shared__ float a0s[64], a1s[64];

    if (tid < 64) {
        int gi = (b << 12) + i0 + tid;
        float m0 = mlM[gi], m1 = mlM[16384 + gi];
        float l0 = mlL[gi], l1 = mlL[16384 + gi];
        float M = fmaxf(m0, m1);
        float w0 = exp2f(m0 - M), w1 = exp2f(m1 - M);
        float gd = gam[0] / (w0 * l0 + w1 * l1);
        a0s[tid] = w0 * gd;
        a1s[tid] = w1 * gd;
    }
    __syncthreads();
#pragma unroll
    for (int k = 0; k < 4; k++) {
        int idx4 = tid + (k << 8);
        int i = idx4 >> 4, c4 = (idx4 & 15) << 2;
        size_t g = ((size_t)((b << 12) + i0 + i)) * 256 + c0 + c4;
        u16x4 p0 = *(const u16x4*)&Op0[g];
        u16x4 p1 = *(const u16x4*)&Op1[g];
        float A0 = a0s[i], A1 = a1s[i];
#pragma unroll
        for (int r = 0; r < 4; r++)
            Tl[c4 + r][i] = A0 * bf2f(p0[r]) + A1 * bf2f(p1[r]);
    }
    __syncthreads();
#pragma unroll
    for (int k = 0; k < 4; k++) {
        int idx4 = tid + (k << 8);
        int c = idx4 >> 4, i4 = (idx4 & 15) << 2;
        size_t g = (((size_t)(b * CIN + c0 + c)) << 12) + i0 + i4;
        float4 xv = *(const float4*)&x1[g];
        float4 o;
        o.x = Tl[c][i4 + 0] + xv.x;
        o.y = Tl[c][i4 + 1] + xv.y;
        o.z = Tl[c][i4 + 2] + xv.z;
        o.w = Tl[c][i4 + 3] + xv.w;
        *(float4*)&out[g] = o;
    }
}

// ---------------------------------------------------------------------------
extern "C" void kernel_launch(void* const* d_in, const int* in_sizes, int n_in,
                              void* d_out, int out_size, void* d_ws, size_t ws_size,
                              hipStream_t stream)
{
    const float* x1  = (const float*)d_in[0];
    const float* x2  = (const float*)d_in[1];
    const float* x3  = (const float*)d_in[2];
    const float* w1  = (const float*)d_in[3];
    const float* b1  = (const float*)d_in[4];
    const float* g1  = (const float*)d_in[5];
    const float* be1 = (const float*)d_in[6];
    const float* m1  = (const float*)d_in[7];
    const float* v1  = (const float*)d_in[8];
    const float* w2  = (const float*)d_in[9];
    const float* b2  = (const float*)d_in[10];
    const float* g2  = (const float*)d_in[11];
    const float* be2 = (const float*)d_in[12];
    const float* m2  = (const float*)d_in[13];
    const float* v2  = (const float*)d_in[14];
    const float* w3  = (const float*)d_in[15];
    const float* b3  = (const float*)d_in[16];
    const float* g3  = (const float*)d_in[17];
    const float* be3 = (const float*)d_in[18];
    const float* m3  = (const float*)d_in[19];
    const float* v3  = (const float*)d_in[20];
    const float* gam = (const float*)d_in[21];

    ushort* Xt1 = (ushort*)d_ws;                     // 4M elems, 8 MB
    ushort* Xt2 = Xt1 + (size_t)4194304;
    ushort* Xt3 = Xt2 + (size_t)4194304;
    ushort* Qw  = Xt3 + (size_t)4194304;             // 1M elems, 2 MB
    ushort* Kw  = Qw  + (size_t)1048576;
    ushort* Vw  = Kw  + (size_t)1048576;             // 4M elems, 8 MB
    ushort* w1c = Vw  + (size_t)4194304;
    ushort* w2c = w1c + 16384;
    ushort* w3c = w2c + 16384;
    float*  bc  = (float*)(w3c + 65536);             // 384 floats
    float*  Qn  = bc + 384;                          // 16384 floats
    unsigned* KmxU = (unsigned*)(Qn + 16384);        // 4

    // dead after the gemms -> reuse for flash partials
    ushort* Op0 = Xt1;                               // 8 MB bf16 [b][i][c]
    ushort* Op1 = Xt2;                               // 8 MB
    float*  mlM = (float*)Xt3;                       // 32768 floats
    float*  mlL = mlM + 32768;

    fuse_tp<<<dim3(64, 4, 13), 256, 0, stream>>>(
        x1, x2, x3,
        w1, b1, g1, be1, m1, v1,
        w2, b2, g2, be2, m2, v2,
        w3, b3, g3, be3, m3, v3,
        Xt1, Xt2, Xt3, w1c, w2c, w3c, bc, KmxU);
    gemm_qkv<<<dim3(64, 4, 4), 256, 0, stream>>>(
        Xt1, Xt2, Xt3, w1c, w2c, w3c, bc, Qw, Kw, Vw, Qn, KmxU);
    flash_mfma<<<256, 1024, 0, stream>>>(Qw, Kw, Vw, Qn, KmxU, Op0, Op1, mlM, mlL);
    merge_out<<<dim3(64, 4, 4), 256, 0, stream>>>(Op0, Op1, mlM, mlL, x1, gam, (float*)d_out);
}